// Round 1
// baseline (430.906 us; speedup 1.0000x reference)
//
#include <hip/hip_runtime.h>
#include <math.h>

#define BB 4
#define NN 8192
#define MM 8192
#define KK 16

// ws float offsets
#define WS_MOM  0      // BB*12
#define WS_SC1  48
#define WS_BI1  112
#define WS_SUM2 176
#define WS_SSQ2 240
#define WS_SC2  304
#define WS_BI2  368
#define WS_CVT  432    // 65536 floats (cv transposed: [c*16+j][o])

// ---------------- cv transpose: cvT[(c*16+j)*64 + o] = cv[o][c][j] ----------------
__global__ __launch_bounds__(256) void k_transpose_cv(const float* __restrict__ cv,
                                                      float* __restrict__ ws) {
    int e = blockIdx.x * 256 + threadIdx.x;
    if (e < 64 * 64 * 16) ws[WS_CVT + e] = cv[(size_t)(e & 63) * 1024 + (e >> 6)];
}

// ---------------- pass 1: per-batch moments of raw pts (pre /nr) ----------------
__global__ __launch_bounds__(256) void k_moments(const float* __restrict__ pos,
                                                 const float* __restrict__ sup,
                                                 const int* __restrict__ nbr,
                                                 float* __restrict__ ws) {
    int b = blockIdx.y;
    int m = blockIdx.x * 256 + threadIdx.x;
    const float* posb = pos + (size_t)b * 3 * NN;
    float sx = sup[((size_t)b * 3 + 0) * MM + m];
    float sy = sup[((size_t)b * 3 + 1) * MM + m];
    float sz = sup[((size_t)b * 3 + 2) * MM + m];
    const int* nb = nbr + ((size_t)b * MM + m) * KK;
    float s[9] = {0, 0, 0, 0, 0, 0, 0, 0, 0};
    for (int k = 0; k < KK; k++) {
        int id = nb[k];
        float px = posb[id] - sx, py = posb[NN + id] - sy, pz = posb[2 * NN + id] - sz;
        s[0] += px; s[1] += py; s[2] += pz;
        s[3] += px * px; s[4] += py * py; s[5] += pz * pz;
        s[6] += px * py; s[7] += px * pz; s[8] += py * pz;
    }
#pragma unroll
    for (int i = 0; i < 9; i++) {
        float v = s[i];
        for (int off = 32; off >= 1; off >>= 1) v += __shfl_down(v, off);
        if ((threadIdx.x & 63) == 0) atomicAdd(&ws[b * 12 + i], v);
    }
}

// ---------------- finalize inorm1 scale/bias from moments ----------------
__global__ void k_fin1(const float* __restrict__ fc1, const float* __restrict__ bn1w,
                       const float* __restrict__ bn1b, const float* __restrict__ nr_,
                       float* __restrict__ ws) {
    int t = threadIdx.x;
    if (t >= 64) return;
    int b = t >> 4, c = t & 15;
    float inv = 1.f / (float)(MM * KK);
    float inr = 1.f / nr_[0];
    const float* S = ws + b * 12;
    float mux = S[0] * inv * inr, muy = S[1] * inv * inr, muz = S[2] * inv * inr;
    float i2 = inv * inr * inr;
    float exx = S[3] * i2, eyy = S[4] * i2, ezz = S[5] * i2;
    float exy = S[6] * i2, exz = S[7] * i2, eyz = S[8] * i2;
    float w0 = fc1[c * 3], w1 = fc1[c * 3 + 1], w2 = fc1[c * 3 + 2];
    float mean = w0 * mux + w1 * muy + w2 * muz;
    float ey2 = w0 * w0 * exx + w1 * w1 * eyy + w2 * w2 * ezz +
                2.f * (w0 * w1 * exy + w0 * w2 * exz + w1 * w2 * eyz);
    float var = fmaxf(ey2 - mean * mean, 0.f);
    float rs = rsqrtf(var + 1e-5f);
    float sc = bn1w[c] * rs;
    ws[WS_SC1 + t] = sc;
    ws[WS_BI1 + t] = bn1b[c] - mean * sc;
}

// ---------------- pass 2: per-(b,c) sum/sumsq of pre-norm fc2 output ----------------
__global__ __launch_bounds__(256) void k_stats2(const float* __restrict__ pos,
                                                const float* __restrict__ sup,
                                                const int* __restrict__ nbr,
                                                const float* __restrict__ alpha_,
                                                const float* __restrict__ beta_,
                                                const float* __restrict__ nr_,
                                                const float* __restrict__ fc1,
                                                const float* __restrict__ fc2,
                                                float* __restrict__ ws) {
    __shared__ float w1[48], w2l[512], sc1[16], bi1[16];
    int t = threadIdx.x;
    int b = blockIdx.y;
    for (int i = t; i < 48; i += 256) w1[i] = fc1[i];
    for (int i = t; i < 512; i += 256) w2l[i] = fc2[i];
    if (t < 16) { sc1[t] = ws[WS_SC1 + b * 16 + t]; bi1[t] = ws[WS_BI1 + b * 16 + t]; }
    __syncthreads();
    int m = blockIdx.x * 256 + t;
    float alpha = alpha_[0], beta = beta_[0], inr = 1.f / nr_[0];
    const float* posb = pos + (size_t)b * 3 * NN;
    float sx = sup[((size_t)b * 3 + 0) * MM + m];
    float sy = sup[((size_t)b * 3 + 1) * MM + m];
    float sz = sup[((size_t)b * 3 + 2) * MM + m];
    const int* nb = nbr + ((size_t)b * MM + m) * KK;
    int idq[KK];
    float sr[KK], q1[16];
#pragma unroll
    for (int j = 0; j < 16; j++) q1[j] = 0.f;
    float S = 0.f;
    for (int k = 0; k < KK; k++) {
        int id = nb[k];
        idq[k] = id;
        float px = posb[id] - sx, py = posb[NN + id] - sy, pz = posb[2 * NN + id] - sz;
        float dd = sqrtf(px * px + py * py + pz * pz);
        float srk = 1.f / (1.f + expf(alpha * dd - beta));
        sr[k] = srk; S += srk;
        px *= inr; py *= inr; pz *= inr;
#pragma unroll
        for (int j = 0; j < 16; j++) {
            float y = w1[j * 3] * px + w1[j * 3 + 1] * py + w1[j * 3 + 2] * pz;
            float v = fmaxf(y * sc1[j] + bi1[j], 0.f);
            q1[j] = fmaxf(q1[j], v * srk);
        }
    }
    S = S + (S == 0.f ? 1.f : 0.f) + 1e-6f;
    float fac = 16.f / S;
    float h2[16];
#pragma unroll
    for (int c = 0; c < 16; c++) {
        float a = 0.f;
#pragma unroll
        for (int i = 0; i < 16; i++) a += w2l[c * 32 + 16 + i] * (q1[i] * fac);
        h2[c] = a;
    }
    float sum2[16], ssq2[16];
#pragma unroll
    for (int c = 0; c < 16; c++) { sum2[c] = 0.f; ssq2[c] = 0.f; }
    for (int k = 0; k < KK; k++) {
        int id = idq[k];
        float px = (posb[id] - sx) * inr, py = (posb[NN + id] - sy) * inr,
              pz = (posb[2 * NN + id] - sz) * inr;
        float m1c[16];
#pragma unroll
        for (int j = 0; j < 16; j++) {
            float y = w1[j * 3] * px + w1[j * 3 + 1] * py + w1[j * 3 + 2] * pz;
            m1c[j] = fmaxf(y * sc1[j] + bi1[j], 0.f);
        }
#pragma unroll
        for (int c = 0; c < 16; c++) {
            float a = h2[c];
#pragma unroll
            for (int i = 0; i < 16; i++) a += w2l[c * 32 + i] * m1c[i];
            sum2[c] += a; ssq2[c] += a * a;
        }
    }
#pragma unroll
    for (int c = 0; c < 16; c++) {
        float v = sum2[c], q = ssq2[c];
        for (int off = 32; off >= 1; off >>= 1) { v += __shfl_down(v, off); q += __shfl_down(q, off); }
        if ((t & 63) == 0) {
            atomicAdd(&ws[WS_SUM2 + b * 16 + c], v);
            atomicAdd(&ws[WS_SSQ2 + b * 16 + c], q);
        }
    }
}

// ---------------- finalize inorm2 ----------------
__global__ void k_fin2(const float* __restrict__ bn2w, const float* __restrict__ bn2b,
                       float* __restrict__ ws) {
    int t = threadIdx.x;
    if (t >= 64) return;
    int c = t & 15;
    float inv = 1.f / (float)(MM * KK);
    float mean = ws[WS_SUM2 + t] * inv;
    float var = fmaxf(ws[WS_SSQ2 + t] * inv - mean * mean, 0.f);
    float rs = rsqrtf(var + 1e-5f);
    float sc = bn2w[c] * rs;
    ws[WS_SC2 + t] = sc;
    ws[WS_BI2 + t] = bn2b[c] - mean * sc;
}

// ---------------- final fused kernel ----------------
__device__ __forceinline__ float gsum16(float v) {
#pragma unroll
    for (int mask = 8; mask >= 1; mask >>= 1) v += __shfl_xor(v, mask, 16);
    return v;
}
__device__ __forceinline__ float gmax16(float v) {
#pragma unroll
    for (int mask = 8; mask >= 1; mask >>= 1) v = fmaxf(v, __shfl_xor(v, mask, 16));
    return v;
}

#define PTS 8   // points per block tile

__global__ __launch_bounds__(256) void k_final(const float* __restrict__ x,
                                               const float* __restrict__ pos,
                                               const float* __restrict__ sup,
                                               const int* __restrict__ nbr,
                                               const float* __restrict__ alpha_,
                                               const float* __restrict__ beta_,
                                               const float* __restrict__ nr_,
                                               const float* __restrict__ fc1,
                                               const float* __restrict__ fc2,
                                               const float* __restrict__ fc3,
                                               const float* __restrict__ ws,
                                               float* __restrict__ out) {
    __shared__ float w1[48], w2l[512], w3l[512];
    __shared__ float s1[16], b1[16], s2[16], b2[16];
    __shared__ int idx_l[PTS][16];
    __shared__ float mat3_l[PTS * 260];          // [p][j*16+k], stride 260 to break conflicts
    __shared__ float feat_l[PTS * 64 * 17];      // [p][c][j] with +1 pad on j-dim
    __shared__ float outb[64 * PTS];             // [o][p]

    int t = threadIdx.x;
    int b = blockIdx.y;
    int m0 = blockIdx.x * PTS;

    for (int i = t; i < 48; i += 256) w1[i] = fc1[i];
    for (int i = t; i < 512; i += 256) w2l[i] = fc2[i];
    for (int i = t; i < 512; i += 256) w3l[i] = fc3[i];
    if (t < 16) {
        s1[t] = ws[WS_SC1 + b * 16 + t]; b1[t] = ws[WS_BI1 + b * 16 + t];
        s2[t] = ws[WS_SC2 + b * 16 + t]; b2[t] = ws[WS_BI2 + b * 16 + t];
    }
    __syncthreads();

    // ---- phase 1: 16 lanes per point compute mat3[16][16] ----
    if (t < PTS * 16) {
        int p = t >> 4, k = t & 15;
        int m = m0 + p;
        float alpha = alpha_[0], beta = beta_[0], inr = 1.f / nr_[0];
        int id = nbr[((size_t)b * MM + m) * KK + k];
        const float* posb = pos + (size_t)b * 3 * NN;
        float px = posb[id] - sup[((size_t)b * 3 + 0) * MM + m];
        float py = posb[NN + id] - sup[((size_t)b * 3 + 1) * MM + m];
        float pz = posb[2 * NN + id] - sup[((size_t)b * 3 + 2) * MM + m];
        float dd = sqrtf(px * px + py * py + pz * pz);
        float sr = 1.f / (1.f + expf(alpha * dd - beta));
        float S = gsum16(sr);
        S = S + (S == 0.f ? 1.f : 0.f) + 1e-6f;
        float dwk = sr * (16.f / S);
        px *= inr; py *= inr; pz *= inr;
        float m1[16];
#pragma unroll
        for (int j = 0; j < 16; j++) {
            float y = w1[j * 3] * px + w1[j * 3 + 1] * py + w1[j * 3 + 2] * pz;
            m1[j] = fmaxf(y * s1[j] + b1[j], 0.f);
        }
        float mp1[16];
#pragma unroll
        for (int j = 0; j < 16; j++) mp1[j] = gmax16(m1[j] * dwk);
        float m2[16];
#pragma unroll
        for (int c = 0; c < 16; c++) {
            float a = 0.f;
#pragma unroll
            for (int i = 0; i < 16; i++)
                a += w2l[c * 32 + i] * m1[i] + w2l[c * 32 + 16 + i] * mp1[i];
            m2[c] = fmaxf(a * s2[c] + b2[c], 0.f);
        }
        float mp2[16];
#pragma unroll
        for (int c = 0; c < 16; c++) mp2[c] = gmax16(m2[c] * dwk);
#pragma unroll
        for (int j = 0; j < 16; j++) {
            float a = 0.f;
#pragma unroll
            for (int i = 0; i < 16; i++)
                a += w3l[j * 32 + i] * m2[i] + w3l[j * 32 + 16 + i] * mp2[i];
            mat3_l[p * 260 + j * 16 + k] = fmaxf(a, 0.f) * dwk;
        }
        idx_l[p][k] = id;
    }
    __syncthreads();

    // ---- phase 2a: feat[p][c][j] = sum_k x_g[c][k] * mat3[p][j][k] ----
    {
        int p = t >> 5, cp = t & 31;
#pragma unroll
        for (int cc2 = 0; cc2 < 2; cc2++) {
            int cc = cp * 2 + cc2;
            const float* xb = x + ((size_t)(b * 64 + cc)) * NN;
            float xv[16];
#pragma unroll
            for (int k = 0; k < 16; k++) xv[k] = xb[idx_l[p][k]];
            float f[16];
#pragma unroll
            for (int j = 0; j < 16; j++) {
                const float4* mrow = (const float4*)&mat3_l[p * 260 + j * 16];
                float a = 0.f;
#pragma unroll
                for (int q = 0; q < 4; q++) {
                    float4 mv = mrow[q];
                    a += xv[q * 4 + 0] * mv.x + xv[q * 4 + 1] * mv.y +
                         xv[q * 4 + 2] * mv.z + xv[q * 4 + 3] * mv.w;
                }
                f[j] = a;
            }
            int fb = (p * 64 + cc) * 17;
#pragma unroll
            for (int j = 0; j < 16; j++) feat_l[fb + j] = f[j];
        }
    }
    __syncthreads();

    // ---- phase 2b: out[o] = sum_{c,j} cvT[c*16+j][o] * feat[p][c][j], 2-pt batch ----
    {
        int o = t & 63, ph = t >> 6;
        int p0 = ph, p1 = ph + 4;
        const float* cvT = ws + WS_CVT;
        float acc0 = 0.f, acc1 = 0.f;
        for (int c = 0; c < 64; c++) {
            int fb0 = (p0 * 64 + c) * 17;
            int fb1 = (p1 * 64 + c) * 17;
            int cvb = c * 16 * 64 + o;
#pragma unroll
            for (int j = 0; j < 16; j++) {
                float w = cvT[cvb + j * 64];
                acc0 += w * feat_l[fb0 + j];
                acc1 += w * feat_l[fb1 + j];
            }
        }
        outb[o * PTS + p0] = acc0;
        outb[o * PTS + p1] = acc1;
    }
    __syncthreads();

    // ---- coalesced-ish output write ----
    for (int e = t; e < 64 * PTS; e += 256) {
        int o2 = e >> 3, p = e & 7;
        out[((size_t)(b * 64 + o2)) * MM + m0 + p] = outb[e];
    }
}

extern "C" void kernel_launch(void* const* d_in, const int* in_sizes, int n_in,
                              void* d_out, int out_size, void* d_ws, size_t ws_size,
                              hipStream_t stream) {
    const float* x    = (const float*)d_in[0];
    const float* pos  = (const float*)d_in[1];
    const float* sup  = (const float*)d_in[2];
    const int*   nbr  = (const int*)d_in[3];
    const float* alp  = (const float*)d_in[4];
    const float* bet  = (const float*)d_in[5];
    const float* nr   = (const float*)d_in[6];
    const float* fc1  = (const float*)d_in[7];
    const float* fc2  = (const float*)d_in[8];
    const float* fc3  = (const float*)d_in[9];
    const float* bn1w = (const float*)d_in[10];
    const float* bn1b = (const float*)d_in[11];
    const float* bn2w = (const float*)d_in[12];
    const float* bn2b = (const float*)d_in[13];
    const float* cv   = (const float*)d_in[14];
    float* out = (float*)d_out;
    float* ws  = (float*)d_ws;

    hipMemsetAsync(d_ws, 0, 432 * sizeof(float), stream);
    k_transpose_cv<<<256, 256, 0, stream>>>(cv, ws);
    k_moments<<<dim3(MM / 256, BB), 256, 0, stream>>>(pos, sup, nbr, ws);
    k_fin1<<<1, 64, 0, stream>>>(fc1, bn1w, bn1b, nr, ws);
    k_stats2<<<dim3(MM / 256, BB), 256, 0, stream>>>(pos, sup, nbr, alp, bet, nr, fc1, fc2, ws);
    k_fin2<<<1, 64, 0, stream>>>(bn2w, bn2b, ws);
    k_final<<<dim3(MM / PTS, BB), 256, 0, stream>>>(x, pos, sup, nbr, alp, bet, nr,
                                                    fc1, fc2, fc3, ws, out);
}

// Round 2
// 295.646 us; speedup vs baseline: 1.4575x; 1.4575x over previous
//
#include <hip/hip_runtime.h>
#include <math.h>

#define BB 4
#define NN 8192
#define MM 8192
#define KK 16

// ws float offsets (stats area)
#define WS_MOM  0      // BB*12
#define WS_SC1  48
#define WS_BI1  112
#define WS_SUM2 176
#define WS_SSQ2 240
#define WS_SC2  304
#define WS_BI2  368
// bf16 cv at byte offset 2048: 64*1024 ushort = 128KB
#define WS_CVB_BYTE 2048

typedef __bf16 bhalf;
typedef bhalf bhalf8 __attribute__((ext_vector_type(8)));
typedef float f32x4 __attribute__((ext_vector_type(4)));
typedef ushort ushort8 __attribute__((ext_vector_type(8)));

static __device__ __forceinline__ ushort f2b(float f) {
    uint u = __builtin_bit_cast(uint, f);
    uint r = (u + 0x7fffu + ((u >> 16) & 1u)) >> 16;
    return (ushort)r;
}

// ---------------- cv -> bf16 (layout already [o][c*16+j] flat) ----------------
__global__ __launch_bounds__(256) void k_prep(const float* __restrict__ cv,
                                              ushort* __restrict__ cvb) {
    int e = blockIdx.x * 256 + threadIdx.x;
    if (e < 64 * 1024) cvb[e] = f2b(cv[e]);
}

// ---------------- pass 1: per-batch moments of raw pts (pre /nr) ----------------
__global__ __launch_bounds__(256) void k_moments(const float* __restrict__ pos,
                                                 const float* __restrict__ sup,
                                                 const int* __restrict__ nbr,
                                                 float* __restrict__ ws) {
    int b = blockIdx.y;
    int m = blockIdx.x * 256 + threadIdx.x;
    const float* posb = pos + (size_t)b * 3 * NN;
    float sx = sup[((size_t)b * 3 + 0) * MM + m];
    float sy = sup[((size_t)b * 3 + 1) * MM + m];
    float sz = sup[((size_t)b * 3 + 2) * MM + m];
    const int* nb = nbr + ((size_t)b * MM + m) * KK;
    float s[9] = {0, 0, 0, 0, 0, 0, 0, 0, 0};
    for (int k = 0; k < KK; k++) {
        int id = nb[k];
        float px = posb[id] - sx, py = posb[NN + id] - sy, pz = posb[2 * NN + id] - sz;
        s[0] += px; s[1] += py; s[2] += pz;
        s[3] += px * px; s[4] += py * py; s[5] += pz * pz;
        s[6] += px * py; s[7] += px * pz; s[8] += py * pz;
    }
#pragma unroll
    for (int i = 0; i < 9; i++) {
        float v = s[i];
        for (int off = 32; off >= 1; off >>= 1) v += __shfl_down(v, off);
        if ((threadIdx.x & 63) == 0) atomicAdd(&ws[b * 12 + i], v);
    }
}

// ---------------- finalize inorm1 scale/bias from moments ----------------
__global__ void k_fin1(const float* __restrict__ fc1, const float* __restrict__ bn1w,
                       const float* __restrict__ bn1b, const float* __restrict__ nr_,
                       float* __restrict__ ws) {
    int t = threadIdx.x;
    if (t >= 64) return;
    int b = t >> 4, c = t & 15;
    float inv = 1.f / (float)(MM * KK);
    float inr = 1.f / nr_[0];
    const float* S = ws + b * 12;
    float mux = S[0] * inv * inr, muy = S[1] * inv * inr, muz = S[2] * inv * inr;
    float i2 = inv * inr * inr;
    float exx = S[3] * i2, eyy = S[4] * i2, ezz = S[5] * i2;
    float exy = S[6] * i2, exz = S[7] * i2, eyz = S[8] * i2;
    float w0 = fc1[c * 3], w1 = fc1[c * 3 + 1], w2 = fc1[c * 3 + 2];
    float mean = w0 * mux + w1 * muy + w2 * muz;
    float ey2 = w0 * w0 * exx + w1 * w1 * eyy + w2 * w2 * ezz +
                2.f * (w0 * w1 * exy + w0 * w2 * exz + w1 * w2 * eyz);
    float var = fmaxf(ey2 - mean * mean, 0.f);
    float rs = rsqrtf(var + 1e-5f);
    float sc = bn1w[c] * rs;
    ws[WS_SC1 + t] = sc;
    ws[WS_BI1 + t] = bn1b[c] - mean * sc;
}

// ---------------- pass 2: per-(b,c) sum/sumsq of pre-norm fc2 output ----------------
__global__ __launch_bounds__(256) void k_stats2(const float* __restrict__ pos,
                                                const float* __restrict__ sup,
                                                const int* __restrict__ nbr,
                                                const float* __restrict__ alpha_,
                                                const float* __restrict__ beta_,
                                                const float* __restrict__ nr_,
                                                const float* __restrict__ fc1,
                                                const float* __restrict__ fc2,
                                                float* __restrict__ ws) {
    __shared__ float w1[48], w2l[512], sc1[16], bi1[16];
    int t = threadIdx.x;
    int b = blockIdx.y;
    for (int i = t; i < 48; i += 256) w1[i] = fc1[i];
    for (int i = t; i < 512; i += 256) w2l[i] = fc2[i];
    if (t < 16) { sc1[t] = ws[WS_SC1 + b * 16 + t]; bi1[t] = ws[WS_BI1 + b * 16 + t]; }
    __syncthreads();
    int m = blockIdx.x * 256 + t;
    float alpha = alpha_[0], beta = beta_[0], inr = 1.f / nr_[0];
    const float* posb = pos + (size_t)b * 3 * NN;
    float sx = sup[((size_t)b * 3 + 0) * MM + m];
    float sy = sup[((size_t)b * 3 + 1) * MM + m];
    float sz = sup[((size_t)b * 3 + 2) * MM + m];
    const int* nb = nbr + ((size_t)b * MM + m) * KK;
    int idq[KK];
    float q1[16];
#pragma unroll
    for (int j = 0; j < 16; j++) q1[j] = 0.f;
    float S = 0.f;
    for (int k = 0; k < KK; k++) {
        int id = nb[k];
        idq[k] = id;
        float px = posb[id] - sx, py = posb[NN + id] - sy, pz = posb[2 * NN + id] - sz;
        float dd = sqrtf(px * px + py * py + pz * pz);
        float srk = 1.f / (1.f + expf(alpha * dd - beta));
        S += srk;
        px *= inr; py *= inr; pz *= inr;
#pragma unroll
        for (int j = 0; j < 16; j++) {
            float y = w1[j * 3] * px + w1[j * 3 + 1] * py + w1[j * 3 + 2] * pz;
            float v = fmaxf(y * sc1[j] + bi1[j], 0.f);
            q1[j] = fmaxf(q1[j], v * srk);
        }
    }
    S = S + (S == 0.f ? 1.f : 0.f) + 1e-6f;
    float fac = 16.f / S;
    float h2[16];
    const float4* w2v = (const float4*)w2l;
#pragma unroll
    for (int c = 0; c < 16; c++) {
        float a = 0.f;
#pragma unroll
        for (int q = 0; q < 4; q++) {
            float4 v = w2v[c * 8 + 4 + q];
            a += v.x * (q1[q * 4] * fac) + v.y * (q1[q * 4 + 1] * fac) +
                 v.z * (q1[q * 4 + 2] * fac) + v.w * (q1[q * 4 + 3] * fac);
        }
        h2[c] = a;
    }
    float sum2[16], ssq2[16];
#pragma unroll
    for (int c = 0; c < 16; c++) { sum2[c] = 0.f; ssq2[c] = 0.f; }
    for (int k = 0; k < KK; k++) {
        int id = idq[k];
        float px = (posb[id] - sx) * inr, py = (posb[NN + id] - sy) * inr,
              pz = (posb[2 * NN + id] - sz) * inr;
        float m1c[16];
#pragma unroll
        for (int j = 0; j < 16; j++) {
            float y = w1[j * 3] * px + w1[j * 3 + 1] * py + w1[j * 3 + 2] * pz;
            m1c[j] = fmaxf(y * sc1[j] + bi1[j], 0.f);
        }
#pragma unroll
        for (int c = 0; c < 16; c++) {
            float a = h2[c];
#pragma unroll
            for (int q = 0; q < 4; q++) {
                float4 v = w2v[c * 8 + q];
                a += v.x * m1c[q * 4] + v.y * m1c[q * 4 + 1] +
                     v.z * m1c[q * 4 + 2] + v.w * m1c[q * 4 + 3];
            }
            sum2[c] += a; ssq2[c] += a * a;
        }
    }
#pragma unroll
    for (int c = 0; c < 16; c++) {
        float v = sum2[c], q = ssq2[c];
        for (int off = 32; off >= 1; off >>= 1) { v += __shfl_down(v, off); q += __shfl_down(q, off); }
        if ((t & 63) == 0) {
            atomicAdd(&ws[WS_SUM2 + b * 16 + c], v);
            atomicAdd(&ws[WS_SSQ2 + b * 16 + c], q);
        }
    }
}

// ---------------- finalize inorm2 ----------------
__global__ void k_fin2(const float* __restrict__ bn2w, const float* __restrict__ bn2b,
                       float* __restrict__ ws) {
    int t = threadIdx.x;
    if (t >= 64) return;
    int c = t & 15;
    float inv = 1.f / (float)(MM * KK);
    float mean = ws[WS_SUM2 + t] * inv;
    float var = fmaxf(ws[WS_SSQ2 + t] * inv - mean * mean, 0.f);
    float rs = rsqrtf(var + 1e-5f);
    float sc = bn2w[c] * rs;
    ws[WS_SC2 + t] = sc;
    ws[WS_BI2 + t] = bn2b[c] - mean * sc;
}

// ---------------- final fused kernel: 16 points/block, MFMA stages ----------------
__device__ __forceinline__ float gsum16(float v) {
#pragma unroll
    for (int mask = 8; mask >= 1; mask >>= 1) v += __shfl_xor(v, mask, 16);
    return v;
}
__device__ __forceinline__ float gmax16(float v) {
#pragma unroll
    for (int mask = 8; mask >= 1; mask >>= 1) v = fmaxf(v, __shfl_xor(v, mask, 16));
    return v;
}

#define PTS 16
#define M3_PSTRIDE 392   // p-stride for mat3_l (elems); j-stride 24
#define FT_PSTRIDE 1032  // p-stride for feat_t (elems)

__global__ __launch_bounds__(256) void k_final(const float* __restrict__ x,
                                               const float* __restrict__ pos,
                                               const float* __restrict__ sup,
                                               const int* __restrict__ nbr,
                                               const float* __restrict__ alpha_,
                                               const float* __restrict__ beta_,
                                               const float* __restrict__ nr_,
                                               const float* __restrict__ fc1,
                                               const float* __restrict__ fc2,
                                               const float* __restrict__ fc3,
                                               const float* __restrict__ ws,
                                               const ushort* __restrict__ cvb,
                                               float* __restrict__ out) {
    __shared__ float w1[48], w2l[512], w3l[512];
    __shared__ float s1[16], b1[16], s2[16], b2[16];
    __shared__ int idx_l[PTS][16];
    __shared__ __align__(16) ushort mat3_l[PTS * M3_PSTRIDE]; // [p][j][k] j-stride 24
    __shared__ __align__(16) ushort feat_t[PTS * FT_PSTRIDE]; // [p][cj] pad to 1032

    int t = threadIdx.x;
    int b = blockIdx.y;
    int m0 = blockIdx.x * PTS;

    for (int i = t; i < 48; i += 256) w1[i] = fc1[i];
    for (int i = t; i < 512; i += 256) w2l[i] = fc2[i];
    for (int i = t; i < 512; i += 256) w3l[i] = fc3[i];
    if (t < 16) {
        s1[t] = ws[WS_SC1 + b * 16 + t]; b1[t] = ws[WS_BI1 + b * 16 + t];
        s2[t] = ws[WS_SC2 + b * 16 + t]; b2[t] = ws[WS_BI2 + b * 16 + t];
    }
    __syncthreads();

    // ---- phase 1: lane (p,k) computes mat3[:,k] for point p ----
    {
        int p = t >> 4, k = t & 15;
        int m = m0 + p;
        float alpha = alpha_[0], beta = beta_[0], inr = 1.f / nr_[0];
        int id = nbr[((size_t)b * MM + m) * KK + k];
        const float* posb = pos + (size_t)b * 3 * NN;
        float px = posb[id] - sup[((size_t)b * 3 + 0) * MM + m];
        float py = posb[NN + id] - sup[((size_t)b * 3 + 1) * MM + m];
        float pz = posb[2 * NN + id] - sup[((size_t)b * 3 + 2) * MM + m];
        float dd = sqrtf(px * px + py * py + pz * pz);
        float sr = 1.f / (1.f + expf(alpha * dd - beta));
        float S = gsum16(sr);
        S = S + (S == 0.f ? 1.f : 0.f) + 1e-6f;
        float dwk = sr * (16.f / S);
        px *= inr; py *= inr; pz *= inr;
        float m1[16];
#pragma unroll
        for (int j = 0; j < 16; j++) {
            float y = w1[j * 3] * px + w1[j * 3 + 1] * py + w1[j * 3 + 2] * pz;
            m1[j] = fmaxf(y * s1[j] + b1[j], 0.f);
        }
        float mp1[16];
#pragma unroll
        for (int j = 0; j < 16; j++) mp1[j] = gmax16(m1[j] * dwk);
        const float4* w2v = (const float4*)w2l;
        float m2[16];
#pragma unroll
        for (int c = 0; c < 16; c++) {
            float a = 0.f;
#pragma unroll
            for (int q = 0; q < 4; q++) {
                float4 v = w2v[c * 8 + q];
                a += v.x * m1[q * 4] + v.y * m1[q * 4 + 1] + v.z * m1[q * 4 + 2] + v.w * m1[q * 4 + 3];
                float4 u = w2v[c * 8 + 4 + q];
                a += u.x * mp1[q * 4] + u.y * mp1[q * 4 + 1] + u.z * mp1[q * 4 + 2] + u.w * mp1[q * 4 + 3];
            }
            m2[c] = fmaxf(a * s2[c] + b2[c], 0.f);
        }
        float mp2[16];
#pragma unroll
        for (int c = 0; c < 16; c++) mp2[c] = gmax16(m2[c] * dwk);
        const float4* w3v = (const float4*)w3l;
#pragma unroll
        for (int j = 0; j < 16; j++) {
            float a = 0.f;
#pragma unroll
            for (int q = 0; q < 4; q++) {
                float4 v = w3v[j * 8 + q];
                a += v.x * m2[q * 4] + v.y * m2[q * 4 + 1] + v.z * m2[q * 4 + 2] + v.w * m2[q * 4 + 3];
                float4 u = w3v[j * 8 + 4 + q];
                a += u.x * mp2[q * 4] + u.y * mp2[q * 4 + 1] + u.z * mp2[q * 4 + 2] + u.w * mp2[q * 4 + 3];
            }
            mat3_l[p * M3_PSTRIDE + j * 24 + k] = f2b(fmaxf(a, 0.f) * dwk);
        }
        idx_l[p][k] = id;
    }
    __syncthreads();

    // ---- stage B (MFMA): feat[p][c,j] = sum_k x[c, idx[p,k]] * mat3[p][j,k] ----
    {
        int w = t >> 6, l = t & 63;
        int lrow = l & 15;          // A: c-within-block / B: j
        int kg = l >> 4;            // 0..3 ; k = kg*8+i (>=16 -> zero pad)
#pragma unroll
        for (int pp = 0; pp < 4; pp++) {
            int p = w * 4 + pp;
            bhalf8 bfrag = {};
            if (kg < 2) {
                ushort8 bu = *(const ushort8*)&mat3_l[p * M3_PSTRIDE + lrow * 24 + kg * 8];
                bfrag = __builtin_bit_cast(bhalf8, bu);
            }
#pragma unroll
            for (int cb = 0; cb < 4; cb++) {
                int c = cb * 16 + lrow;
                bhalf8 afrag = {};
                if (kg < 2) {
                    const float* xc = x + ((size_t)(b * 64 + c)) * NN;
                    ushort8 au;
#pragma unroll
                    for (int i = 0; i < 8; i++) au[i] = f2b(xc[idx_l[p][kg * 8 + i]]);
                    afrag = __builtin_bit_cast(bhalf8, au);
                }
                f32x4 d = {0.f, 0.f, 0.f, 0.f};
                d = __builtin_amdgcn_mfma_f32_16x16x32_bf16(afrag, bfrag, d, 0, 0, 0);
#pragma unroll
                for (int r = 0; r < 4; r++) {
                    int crow = cb * 16 + kg * 4 + r;     // D row = c
                    feat_t[p * FT_PSTRIDE + crow * 16 + lrow] = f2b(d[r]); // col = j
                }
            }
        }
    }
    __syncthreads();

    // ---- stage C (MFMA): out[o, p] = sum_cj cvb[o,cj] * feat[cj,p] ----
    {
        int w = t >> 6, l = t & 63;
        int lo = l & 15;            // A row (o-offset) / B col (p)
        int kg = l >> 4;            // k-subgroup
        const ushort* arow = cvb + (size_t)(w * 16 + lo) * 1024 + kg * 8;
        const ushort* brow = feat_t + lo * FT_PSTRIDE + kg * 8;
        f32x4 acc = {0.f, 0.f, 0.f, 0.f};
#pragma unroll
        for (int kt = 0; kt < 32; kt++) {
            ushort8 au = *(const ushort8*)(arow + kt * 32);
            ushort8 bu = *(const ushort8*)(brow + kt * 32);
            acc = __builtin_amdgcn_mfma_f32_16x16x32_bf16(
                __builtin_bit_cast(bhalf8, au), __builtin_bit_cast(bhalf8, bu), acc, 0, 0, 0);
        }
#pragma unroll
        for (int r = 0; r < 4; r++) {
            int o = w * 16 + kg * 4 + r;
            out[((size_t)(b * 64 + o)) * MM + m0 + lo] = acc[r];
        }
    }
}

extern "C" void kernel_launch(void* const* d_in, const int* in_sizes, int n_in,
                              void* d_out, int out_size, void* d_ws, size_t ws_size,
                              hipStream_t stream) {
    const float* x    = (const float*)d_in[0];
    const float* pos  = (const float*)d_in[1];
    const float* sup  = (const float*)d_in[2];
    const int*   nbr  = (const int*)d_in[3];
    const float* alp  = (const float*)d_in[4];
    const float* bet  = (const float*)d_in[5];
    const float* nr   = (const float*)d_in[6];
    const float* fc1  = (const float*)d_in[7];
    const float* fc2  = (const float*)d_in[8];
    const float* fc3  = (const float*)d_in[9];
    const float* bn1w = (const float*)d_in[10];
    const float* bn1b = (const float*)d_in[11];
    const float* bn2w = (const float*)d_in[12];
    const float* bn2b = (const float*)d_in[13];
    const float* cv   = (const float*)d_in[14];
    float* out = (float*)d_out;
    float* ws  = (float*)d_ws;
    ushort* cvb = (ushort*)((char*)d_ws + WS_CVB_BYTE);

    hipMemsetAsync(d_ws, 0, 432 * sizeof(float), stream);
    k_prep<<<256, 256, 0, stream>>>(cv, cvb);
    k_moments<<<dim3(MM / 256, BB), 256, 0, stream>>>(pos, sup, nbr, ws);
    k_fin1<<<1, 64, 0, stream>>>(fc1, bn1w, bn1b, nr, ws);
    k_stats2<<<dim3(MM / 256, BB), 256, 0, stream>>>(pos, sup, nbr, alp, bet, nr, fc1, fc2, ws);
    k_fin2<<<1, 64, 0, stream>>>(bn2w, bn2b, ws);
    k_final<<<dim3(MM / PTS, BB), 256, 0, stream>>>(x, pos, sup, nbr, alp, bet, nr,
                                                    fc1, fc2, fc3, ws, cvb, out);
}

// Round 4
// 236.604 us; speedup vs baseline: 1.8212x; 1.2495x over previous
//
#include <hip/hip_runtime.h>
#include <math.h>

#define BB 4
#define NN 8192
#define MM 8192
#define KK 16

// ws float-offsets (stats area)
#define WS_MOM  0      // BB*12
#define WS_SUM2 176
#define WS_SSQ2 240
// byte offsets for big scratch
#define WS_CVB_BYTE 2048                        // 64*1024 ush = 131072 B
#define WS_XT_BYTE  (WS_CVB_BYTE + 131072)      // 4*8192*64 ush = 4194304 B
#define WS_PT_BYTE  (WS_XT_BYTE + 4194304)      // 4*8192*4 f32 = 524288 B

typedef __bf16 bhalf;
typedef bhalf bhalf8 __attribute__((ext_vector_type(8)));
typedef float f32x4 __attribute__((ext_vector_type(4)));
typedef ushort ushort8v __attribute__((ext_vector_type(8)));
typedef ushort ushort4v __attribute__((ext_vector_type(4)));

static __device__ __forceinline__ ushort f2b(float f) {
    uint u = __builtin_bit_cast(uint, f);
    uint r = (u + 0x7fffu + ((u >> 16) & 1u)) >> 16;
    return (ushort)r;
}

__device__ __forceinline__ float gsum16(float v) {
#pragma unroll
    for (int mask = 8; mask >= 1; mask >>= 1) v += __shfl_xor(v, mask);
    return v;
}
__device__ __forceinline__ float gmax16(float v) {
#pragma unroll
    for (int mask = 8; mask >= 1; mask >>= 1) v = fmaxf(v, __shfl_xor(v, mask));
    return v;
}

// ---------------- k_pre: xT transpose+bf16, posT, cvb, moments ----------------
__global__ __launch_bounds__(256) void k_pre(const float* __restrict__ x,
                                             const float* __restrict__ pos,
                                             const float* __restrict__ sup,
                                             const int* __restrict__ nbr,
                                             const float* __restrict__ cv,
                                             float* __restrict__ ws,
                                             ushort* __restrict__ cvb,
                                             ushort* __restrict__ xT,
                                             float* __restrict__ posT) {
    int bid = blockIdx.x, t = threadIdx.x;
    if (bid < 512) {
        int b = bid >> 7, n0 = (bid & 127) * 64;
        __shared__ ushort tile[64 * 66];
        const float* xb = x + (size_t)b * 64 * NN;
#pragma unroll
        for (int i = 0; i < 16; i++) {
            int c = i * 4 + (t >> 6), n = t & 63;
            tile[c * 66 + n] = f2b(xb[(size_t)c * NN + n0 + n]);
        }
        __syncthreads();
#pragma unroll
        for (int i = 0; i < 16; i++) {
            int n = i * 4 + (t >> 6), c = t & 63;
            xT[((size_t)b * NN + n0 + n) * 64 + c] = tile[c * 66 + n];
        }
        int nl = t >> 2, d = t & 3;
        float v = (d < 3) ? pos[((size_t)b * 3 + d) * NN + n0 + nl] : 0.f;
        posT[((size_t)b * NN + n0 + nl) * 4 + d] = v;
    } else if (bid < 576) {
        int e = (bid - 512) * 1024 + t * 4;
        float4 cvv = *(const float4*)(cv + e);
        ushort4v o = {f2b(cvv.x), f2b(cvv.y), f2b(cvv.z), f2b(cvv.w)};
        *(ushort4v*)(cvb + e) = o;
    } else {
        int rem = bid - 576;
        int b = rem & 3, m = (rem >> 2) * 256 + t;
        const float* posb = pos + (size_t)b * 3 * NN;
        float sx = sup[((size_t)b * 3 + 0) * MM + m];
        float sy = sup[((size_t)b * 3 + 1) * MM + m];
        float sz = sup[((size_t)b * 3 + 2) * MM + m];
        const int* nb = nbr + ((size_t)b * MM + m) * KK;
        float s[9] = {0, 0, 0, 0, 0, 0, 0, 0, 0};
        for (int k = 0; k < KK; k++) {
            int id = nb[k];
            float px = posb[id] - sx, py = posb[NN + id] - sy, pz = posb[2 * NN + id] - sz;
            s[0] += px; s[1] += py; s[2] += pz;
            s[3] += px * px; s[4] += py * py; s[5] += pz * pz;
            s[6] += px * py; s[7] += px * pz; s[8] += py * pz;
        }
#pragma unroll
        for (int i = 0; i < 9; i++) {
            float v = s[i];
            for (int off = 32; off >= 1; off >>= 1) v += __shfl_down(v, off);
            if ((t & 63) == 0) atomicAdd(&ws[b * 12 + i], v);
        }
    }
}

// ---------------- k_stats2: per-(b,c) sum/sumsq of pre-norm fc2 output ----------------
__global__ __launch_bounds__(128) void k_stats2(const float* __restrict__ sup,
                                                const int* __restrict__ nbr,
                                                const float* __restrict__ alpha_,
                                                const float* __restrict__ beta_,
                                                const float* __restrict__ nr_,
                                                const float* __restrict__ fc1,
                                                const float* __restrict__ fc2,
                                                const float* __restrict__ bn1w,
                                                const float* __restrict__ bn1b,
                                                const float* __restrict__ posT,
                                                float* __restrict__ ws) {
    __shared__ float w1[48], w2l[512], sc1[16], bi1[16];
    int t = threadIdx.x, b = blockIdx.y;
    for (int i = t; i < 48; i += 128) w1[i] = fc1[i];
    for (int i = t; i < 512; i += 128) w2l[i] = fc2[i];
    if (t < 16) {
        float inv = 1.f / (float)(MM * KK);
        float inr = 1.f / nr_[0];
        const float* S = ws + b * 12;
        float mux = S[0] * inv * inr, muy = S[1] * inv * inr, muz = S[2] * inv * inr;
        float i2 = inv * inr * inr;
        float w0 = fc1[t * 3], w1v = fc1[t * 3 + 1], w2v = fc1[t * 3 + 2];
        float mean = w0 * mux + w1v * muy + w2v * muz;
        float ey2 = w0 * w0 * S[3] * i2 + w1v * w1v * S[4] * i2 + w2v * w2v * S[5] * i2 +
                    2.f * (w0 * w1v * S[6] * i2 + w0 * w2v * S[7] * i2 + w1v * w2v * S[8] * i2);
        float var = fmaxf(ey2 - mean * mean, 0.f);
        float rs = rsqrtf(var + 1e-5f);
        sc1[t] = bn1w[t] * rs;
        bi1[t] = bn1b[t] - mean * sc1[t];
    }
    __syncthreads();
    int mi = t >> 1, kh = t & 1;
    int m = blockIdx.x * 64 + mi;
    float alpha = alpha_[0], beta = beta_[0], inr = 1.f / nr_[0];
    float sx = sup[((size_t)b * 3 + 0) * MM + m];
    float sy = sup[((size_t)b * 3 + 1) * MM + m];
    float sz = sup[((size_t)b * 3 + 2) * MM + m];
    const int* nb = nbr + ((size_t)b * MM + m) * KK + kh * 8;
    float nx[8], ny[8], nz[8], q1[16];
#pragma unroll
    for (int j = 0; j < 16; j++) q1[j] = 0.f;
    float S = 0.f;
#pragma unroll
    for (int kk = 0; kk < 8; kk++) {
        int id = nb[kk];
        float4 pv = *(const float4*)(posT + ((size_t)b * NN + id) * 4);
        float rx = pv.x - sx, ry = pv.y - sy, rz = pv.z - sz;
        float dd = sqrtf(rx * rx + ry * ry + rz * rz);
        float srk = 1.f / (1.f + expf(alpha * dd - beta));
        S += srk;
        nx[kk] = rx * inr; ny[kk] = ry * inr; nz[kk] = rz * inr;
#pragma unroll
        for (int j = 0; j < 16; j++) {
            float y = w1[j * 3] * nx[kk] + w1[j * 3 + 1] * ny[kk] + w1[j * 3 + 2] * nz[kk];
            float v = fmaxf(y * sc1[j] + bi1[j], 0.f);
            q1[j] = fmaxf(q1[j], v * srk);
        }
    }
    S += __shfl_xor(S, 1);
#pragma unroll
    for (int j = 0; j < 16; j++) q1[j] = fmaxf(q1[j], __shfl_xor(q1[j], 1));
    S = S + (S == 0.f ? 1.f : 0.f) + 1e-6f;
    float fac = 16.f / S;
    const float4* w2v4 = (const float4*)w2l;
    float h2[16];
#pragma unroll
    for (int c = 0; c < 16; c++) {
        float a = 0.f;
#pragma unroll
        for (int q = 0; q < 4; q++) {
            float4 v = w2v4[c * 8 + 4 + q];
            a += v.x * (q1[q * 4] * fac) + v.y * (q1[q * 4 + 1] * fac) +
                 v.z * (q1[q * 4 + 2] * fac) + v.w * (q1[q * 4 + 3] * fac);
        }
        h2[c] = a;
    }
    float sum2[16], ssq2[16];
#pragma unroll
    for (int c = 0; c < 16; c++) { sum2[c] = 0.f; ssq2[c] = 0.f; }
#pragma unroll
    for (int kk = 0; kk < 8; kk++) {
        float m1c[16];
#pragma unroll
        for (int j = 0; j < 16; j++) {
            float y = w1[j * 3] * nx[kk] + w1[j * 3 + 1] * ny[kk] + w1[j * 3 + 2] * nz[kk];
            m1c[j] = fmaxf(y * sc1[j] + bi1[j], 0.f);
        }
#pragma unroll
        for (int c = 0; c < 16; c++) {
            float a = h2[c];
#pragma unroll
            for (int q = 0; q < 4; q++) {
                float4 v = w2v4[c * 8 + q];
                a += v.x * m1c[q * 4] + v.y * m1c[q * 4 + 1] +
                     v.z * m1c[q * 4 + 2] + v.w * m1c[q * 4 + 3];
            }
            sum2[c] += a; ssq2[c] += a * a;
        }
    }
#pragma unroll
    for (int c = 0; c < 16; c++) {
        float v = sum2[c], q = ssq2[c];
        for (int off = 32; off >= 1; off >>= 1) { v += __shfl_down(v, off); q += __shfl_down(q, off); }
        if ((t & 63) == 0) {
            atomicAdd(&ws[WS_SUM2 + b * 16 + c], v);
            atomicAdd(&ws[WS_SSQ2 + b * 16 + c], q);
        }
    }
}

// ---------------- k_final: 16 points/block; fp32 phase 1 + MFMA stages B/C ----------------
__global__ __launch_bounds__(256) void k_final(const float* __restrict__ sup,
                                               const int* __restrict__ nbr,
                                               const float* __restrict__ alpha_,
                                               const float* __restrict__ beta_,
                                               const float* __restrict__ nr_,
                                               const float* __restrict__ fc1,
                                               const float* __restrict__ fc2,
                                               const float* __restrict__ fc3,
                                               const float* __restrict__ bn1w,
                                               const float* __restrict__ bn1b,
                                               const float* __restrict__ bn2w,
                                               const float* __restrict__ bn2b,
                                               const float* __restrict__ ws,
                                               const ushort* __restrict__ cvb,
                                               const ushort* __restrict__ xT,
                                               const float* __restrict__ posT,
                                               float* __restrict__ out) {
    __shared__ float w1[48], w2l[512], w3l[512];
    __shared__ float s1[16], b1[16], s2[16], b2[16];
    __shared__ __align__(16) ushort ov[16 * 1040];   // per point: xg[c][k], then feat[cj] overlay
    __shared__ __align__(16) ushort m3l[16 * 384];   // [p][j*24 + k]

    int t = threadIdx.x;
    int b = blockIdx.y;
    int m0 = blockIdx.x * 16;
    int w = t >> 6, l = t & 63;
    int lk = l & 15, kg = l >> 4;
    int ps = t >> 4, ks = t & 15;

    // ---- staging loads issued early (latency hidden under setup + phase 1) ----
    int idxt = nbr[((size_t)b * MM + m0 + ps) * KK + ks];
    float4 pf = *(const float4*)(posT + ((size_t)b * NN + idxt) * 4);
    const ushort8v* xrow = (const ushort8v*)(xT + ((size_t)b * NN + idxt) * 64);
    ushort8v g0 = xrow[0], g1 = xrow[1], g2 = xrow[2], g3 = xrow[3];
    ushort8v g4 = xrow[4], g5 = xrow[5], g6 = xrow[6], g7 = xrow[7];

    float alpha = alpha_[0], beta = beta_[0], inr = 1.f / nr_[0];

    for (int i = t; i < 48; i += 256) w1[i] = fc1[i];
    for (int i = t; i < 512; i += 256) w2l[i] = fc2[i];
    for (int i = t; i < 512; i += 256) w3l[i] = fc3[i];
    if (t < 16) {
        float inv = 1.f / (float)(MM * KK);
        const float* MO = ws + b * 12;
        float mux = MO[0] * inv * inr, muy = MO[1] * inv * inr, muz = MO[2] * inv * inr;
        float i2 = inv * inr * inr;
        float w0 = fc1[t * 3], wa = fc1[t * 3 + 1], wb = fc1[t * 3 + 2];
        float mean = w0 * mux + wa * muy + wb * muz;
        float ey2 = w0 * w0 * MO[3] * i2 + wa * wa * MO[4] * i2 + wb * wb * MO[5] * i2 +
                    2.f * (w0 * wa * MO[6] * i2 + w0 * wb * MO[7] * i2 + wa * wb * MO[8] * i2);
        float var = fmaxf(ey2 - mean * mean, 0.f);
        float rs = rsqrtf(var + 1e-5f);
        s1[t] = bn1w[t] * rs;
        b1[t] = bn1b[t] - mean * s1[t];
        float mean2 = ws[WS_SUM2 + b * 16 + t] * inv;
        float var2 = fmaxf(ws[WS_SSQ2 + b * 16 + t] * inv - mean2 * mean2, 0.f);
        float rs2 = rsqrtf(var2 + 1e-5f);
        s2[t] = bn2w[t] * rs2;
        b2[t] = bn2b[t] - mean2 * s2[t];
    }
    __syncthreads();

    // ---- phase 1 (fp32, R2-proven math): lane = (point ps, neighbor ks) ----
    {
        int mm = m0 + ps;
        float rx = pf.x - sup[((size_t)b * 3 + 0) * MM + mm];
        float ry = pf.y - sup[((size_t)b * 3 + 1) * MM + mm];
        float rz = pf.z - sup[((size_t)b * 3 + 2) * MM + mm];
        float dd = sqrtf(rx * rx + ry * ry + rz * rz);
        float sr = 1.f / (1.f + expf(alpha * dd - beta));
        float S = gsum16(sr);
        S = S + (S == 0.f ? 1.f : 0.f) + 1e-6f;
        float dwk = sr * (16.f / S);
        float nxv = rx * inr, nyv = ry * inr, nzv = rz * inr;

        float m1v[16], mp1[16];
#pragma unroll
        for (int j = 0; j < 16; j++) {
            float y = w1[j * 3] * nxv + w1[j * 3 + 1] * nyv + w1[j * 3 + 2] * nzv;
            m1v[j] = fmaxf(y * s1[j] + b1[j], 0.f);
        }
#pragma unroll
        for (int j = 0; j < 16; j++) mp1[j] = gmax16(m1v[j] * dwk);

        const float4* w2v = (const float4*)w2l;
        float m2v[16], mp2[16];
#pragma unroll
        for (int c = 0; c < 16; c++) {
            float a = 0.f;
#pragma unroll
            for (int q = 0; q < 4; q++) {
                float4 v = w2v[c * 8 + q];
                a += v.x * m1v[q * 4] + v.y * m1v[q * 4 + 1] + v.z * m1v[q * 4 + 2] + v.w * m1v[q * 4 + 3];
                float4 u = w2v[c * 8 + 4 + q];
                a += u.x * mp1[q * 4] + u.y * mp1[q * 4 + 1] + u.z * mp1[q * 4 + 2] + u.w * mp1[q * 4 + 3];
            }
            m2v[c] = fmaxf(a * s2[c] + b2[c], 0.f);
        }
#pragma unroll
        for (int c = 0; c < 16; c++) mp2[c] = gmax16(m2v[c] * dwk);

        const float4* w3v = (const float4*)w3l;
        ushort* m3p = m3l + ps * 384;
#pragma unroll
        for (int j = 0; j < 16; j++) {
            float a = 0.f;
#pragma unroll
            for (int q = 0; q < 4; q++) {
                float4 v = w3v[j * 8 + q];
                a += v.x * m2v[q * 4] + v.y * m2v[q * 4 + 1] + v.z * m2v[q * 4 + 2] + v.w * m2v[q * 4 + 3];
                float4 u = w3v[j * 8 + 4 + q];
                a += u.x * mp2[q * 4] + u.y * mp2[q * 4 + 1] + u.z * mp2[q * 4 + 2] + u.w * mp2[q * 4 + 3];
            }
            m3p[j * 24 + ks] = f2b(fmaxf(a, 0.f) * dwk);
        }
    }

    // ---- write staged xg rows: ov[p][c*16 + k] ----
    {
        ushort* ovp = ov + ps * 1040;
#define STG(gv, h) _Pragma("unroll") for (int i2 = 0; i2 < 8; i2++) ovp[((h) * 8 + i2) * 16 + ks] = (ushort)gv[i2];
        STG(g0, 0) STG(g1, 1) STG(g2, 2) STG(g3, 3)
        STG(g4, 4) STG(g5, 5) STG(g6, 6) STG(g7, 7)
#undef STG
    }
    __syncthreads();

    const f32x4 zz = {0.f, 0.f, 0.f, 0.f};

    // ---- stage B (MFMA): feat[j][c] = sum_k mat3[j][k] * xg[c][k]; overlay feat onto ov ----
#pragma unroll
    for (int pp = 0; pp < 4; pp++) {
        int p = w * 4 + pp;
        bhalf8 afr = {};
        if (kg < 2) afr = __builtin_bit_cast(bhalf8, *(ushort8v*)(m3l + p * 384 + lk * 24 + kg * 8));
        ushort* ovb = ov + p * 1040;
#pragma unroll
        for (int cb = 0; cb < 4; cb++) {
            bhalf8 bfr = {};
            if (kg < 2) bfr = __builtin_bit_cast(bhalf8, *(ushort8v*)(ovb + (cb * 16 + lk) * 16 + kg * 8));
            f32x4 dF = __builtin_amdgcn_mfma_f32_16x16x32_bf16(afr, bfr, zz, 0, 0, 0);
            ushort4v fw = {f2b(dF[0]), f2b(dF[1]), f2b(dF[2]), f2b(dF[3])};
            *(ushort4v*)(ovb + (cb * 16 + lk) * 16 + kg * 4) = fw;
        }
    }
    __syncthreads();

    // ---- stage C (MFMA): out[o][p] = sum_cj cvb[o][cj] * feat[p][cj] ----
    {
        const ushort* arow = cvb + (size_t)(w * 16 + lk) * 1024;
        const ushort* brow = ov + lk * 1040;
        f32x4 acc = zz;
#pragma unroll
        for (int kt = 0; kt < 32; kt++) {
            bhalf8 au = __builtin_bit_cast(bhalf8, *(const ushort8v*)(arow + kt * 32 + kg * 8));
            bhalf8 bu = __builtin_bit_cast(bhalf8, *(const ushort8v*)(brow + kt * 32 + kg * 8));
            acc = __builtin_amdgcn_mfma_f32_16x16x32_bf16(au, bu, acc, 0, 0, 0);
        }
#pragma unroll
        for (int r = 0; r < 4; r++) {
            int o = w * 16 + kg * 4 + r;
            out[((size_t)(b * 64 + o)) * MM + m0 + lk] = acc[r];
        }
    }
}

extern "C" void kernel_launch(void* const* d_in, const int* in_sizes, int n_in,
                              void* d_out, int out_size, void* d_ws, size_t ws_size,
                              hipStream_t stream) {
    const float* x    = (const float*)d_in[0];
    const float* pos  = (const float*)d_in[1];
    const float* sup  = (const float*)d_in[2];
    const int*   nbr  = (const int*)d_in[3];
    const float* alp  = (const float*)d_in[4];
    const float* bet  = (const float*)d_in[5];
    const float* nr   = (const float*)d_in[6];
    const float* fc1  = (const float*)d_in[7];
    const float* fc2  = (const float*)d_in[8];
    const float* fc3  = (const float*)d_in[9];
    const float* bn1w = (const float*)d_in[10];
    const float* bn1b = (const float*)d_in[11];
    const float* bn2w = (const float*)d_in[12];
    const float* bn2b = (const float*)d_in[13];
    const float* cv   = (const float*)d_in[14];
    float* out = (float*)d_out;
    float* ws  = (float*)d_ws;
    ushort* cvb = (ushort*)((char*)d_ws + WS_CVB_BYTE);
    ushort* xT  = (ushort*)((char*)d_ws + WS_XT_BYTE);
    float*  posT = (float*)((char*)d_ws + WS_PT_BYTE);

    hipMemsetAsync(d_ws, 0, 432 * sizeof(float), stream);
    k_pre<<<704, 256, 0, stream>>>(x, pos, sup, nbr, cv, ws, cvb, xT, posT);
    k_stats2<<<dim3(128, BB), 128, 0, stream>>>(sup, nbr, alp, bet, nr, fc1, fc2,
                                                bn1w, bn1b, posT, ws);
    k_final<<<dim3(512, BB), 256, 0, stream>>>(sup, nbr, alp, bet, nr, fc1, fc2, fc3,
                                               bn1w, bn1b, bn2w, bn2b, ws, cvb, xT, posT, out);
}